// Round 6
// baseline (204.484 us; speedup 1.0000x reference)
//
#include <hip/hip_runtime.h>
#include <stdint.h>

// EdgeAwareMultiHeadAttention on MI355X (gfx950) — round 12
// Changes vs round 11:
//  * prep_kernel ELIMINATED (4 kernels -> 3). Attribution across r6-r11:
//    flash 61.5us + GEMM roofline ~20us != 185us total; non-flash residual
//    pinned at ~124-130us regardless of GEMM structure -> fixed per-launch
//    overhead suspected (rocprof.md: ~10us/launch can dominate).
//  * gemm_qkv now stages A from f32 x and B from f32 Wq/Wk/Wv directly,
//    converting to bf16 during the LDS write (same (__bf16) rounding ->
//    bit-identical numerics). gemm_out stages B from f32 Wo likewise.
//  * edge-MLP coefficient computation moved to top of gemm_qkv block (0,0)
//    (only flash reads co; gemm_qkv completes first -> safe).
//  * flash kernel UNTOUCHED from r11 (61.4us best measured).

#define SEQ 2048
#define EMB 512
#define NH  8
#define HD  64
#define NB  2
#define L2E 1.4426950408889634f

typedef unsigned int   u32;
typedef unsigned short u16;
typedef u32   u32x4  __attribute__((ext_vector_type(4)));
typedef float f32x4  __attribute__((ext_vector_type(4)));
typedef __bf16 bf16x8 __attribute__((ext_vector_type(8)));

#define MFMA16(a, b, c) __builtin_amdgcn_mfma_f32_16x16x32_bf16((a), (b), (c), 0, 0, 0)

static __device__ __forceinline__ u16 f2bf(float f) {
  return __builtin_bit_cast(u16, (__bf16)f);
}
static __device__ __forceinline__ u32 pack2(float a, float b) {
  return (u32)f2bf(a) | ((u32)f2bf(b) << 16);
}
static __device__ __forceinline__ bf16x8 ldfrag(const u16* p) {
  return __builtin_bit_cast(bf16x8, *(const u32x4*)p);
}
// async global->LDS, 16B per lane (dst = wave-uniform base + lane*16)
static __device__ __forceinline__ void glds16(const u16* g, u16* l) {
  __builtin_amdgcn_global_load_lds(
      (const __attribute__((address_space(1))) u32*)(const void*)g,
      (__attribute__((address_space(3))) u32*)(void*)l, 16, 0, 0);
}
// 8 f32 -> 4x bf16x2 (RTN via (__bf16) cast, same as old prep path)
static __device__ __forceinline__ u32x4 cvt4(float4 a, float4 b) {
  u32x4 r;
  r[0] = pack2(a.x, a.y); r[1] = pack2(a.z, a.w);
  r[2] = pack2(b.x, b.y); r[3] = pack2(b.z, b.w);
  return r;
}
// combine two bf16 pairs with scale: (bf(a)+bf(d))*rl, repacked to bf16x2
static __device__ __forceinline__ u32 comb2(u32 a, u32 d, float rl) {
  float lo = __builtin_bit_cast(float, a << 16)
           + __builtin_bit_cast(float, d << 16);
  float hi = __builtin_bit_cast(float, a & 0xffff0000u)
           + __builtin_bit_cast(float, d & 0xffff0000u);
  return pack2(lo * rl, hi * rl);
}
static __device__ __forceinline__ u32x4 comb4(u32x4 a, u32x4 d, float rl) {
  u32x4 r;
  r[0] = comb2(a[0], d[0], rl); r[1] = comb2(a[1], d[1], rl);
  r[2] = comb2(a[2], d[2], rl); r[3] = comb2(a[3], d[3], rl);
  return r;
}

// Fragment-major layouts, per (b,h) plane of 131072 u16 (2048x64):
//  ksw: (n,d) -> (n>>4)*1024 + (d>>5)*512 + (((d>>3)&3)*16 + (n&15))*8 + (d&7)
//  vsw: (n,d) -> (n>>6)*4096 + (d>>4)*1024 + ((n>>5)&1)*512
//               + (((n>>3)&3)*16 + (d&15))*8 + (n&7)
// One 64-j tile = 4096 u16 contiguous -> LDS image is a straight copy.

// ---------------------------------------------------------------- k1: QKV GEMM 64x128, BK=64
// Stages directly from f32 inputs (absorbs old prep_kernel); block (0,0)
// additionally computes the edge-MLP coefficient table co[].
#define LDB 72
__global__ __launch_bounds__(256) void gemm_qkv_kernel(
    const float* __restrict__ x,
    const float* __restrict__ Wq, const float* __restrict__ Wk, const float* __restrict__ Wv,
    const float* __restrict__ bq, const float* __restrict__ bk, const float* __restrict__ bv,
    const float* __restrict__ We1, const float* __restrict__ be1,
    const float* __restrict__ We2, const float* __restrict__ be2,
    const float* __restrict__ ebias,
    u16* __restrict__ qh, u16* __restrict__ ksw, u16* __restrict__ vsw,
    float* __restrict__ co)
{
  __shared__ u16 sm[64 * LDB + 128 * LDB];   // As | Bs (27.6KB), reused by epilogue
  u16* As = sm;
  u16* Bs = sm + 64 * LDB;
  const int tid = threadIdx.x;

  // ---- edge-MLP coefficients (block (0,0) only; flash reads co later) ----
  if (blockIdx.x == 0 && blockIdx.y == 0) {
    const int e = tid & 15, h2 = tid >> 4;
    if (tid < 128) {
      co[49 + e * 8 + h2] = 0.0f;
      if (h2 == 0) { co[17 + e] = 0.0f; co[33 + e] = 0.0f; }
    }
    __syncthreads();
    if (tid < 128) {
      float w1 = We1[e], b1 = be1[e], w2 = We2[h2 * 16 + e];
      float u0 = b1, u1 = w1 + b1;
      bool on  = (u0 >= 0.0f) && (u1 >= 0.0f);
      bool off = (u0 <= 0.0f) && (u1 <= 0.0f);
      bool crossing = (!on) && (!off);
      float ca = on ? (w2 * b1) : (crossing ? 0.5f * w2 * b1 : 0.0f);
      float cb = on ? (w2 * w1) : (crossing ? 0.5f * w2 * w1 : 0.0f);
      #pragma unroll
      for (int d = 1; d < 16; d <<= 1) { ca += __shfl_xor(ca, d); cb += __shfl_xor(cb, d); }
      if (e == 0) { co[h2] = (be2[h2] + ca) * L2E; co[8 + h2] = (ebias[h2] + cb) * L2E; }
      unsigned long long msk = __ballot(crossing);
      int midx = __popcll(msk & 0xFFFFull & ((1ull << e) - 1ull));
      int mcnt = __popcll(msk & 0xFFFFull);
      if (crossing) {
        co[49 + midx * 8 + h2] = 0.5f * w2 * L2E;
        if (h2 == 0) { co[17 + midx] = w1; co[33 + midx] = b1; }
      }
      if (tid == 0) ((int*)co)[16] = mcnt;
    }
  }

  const int lane = tid & 63, w = tid >> 6;
  const int q = lane >> 4, l15 = lane & 15;
  const int m0 = blockIdx.y * 64;
  const int n0 = blockIdx.x * 128;

  f32x4 acc[4][2];
  f32x4 zero = {0.f, 0.f, 0.f, 0.f};
  #pragma unroll
  for (int i = 0; i < 4; i++) { acc[i][0] = zero; acc[i][1] = zero; }

  // staging map: A 64 rows x 64 k -> 4 thr/row (16 elems each, f32 source);
  //              B 128 rows x 64 k -> 2 thr/row (32 elems each, f32 source)
  const int ar = tid >> 2, aq = tid & 3;
  const int br = tid >> 1, bh2 = tid & 1;
  const int mat = n0 >> 9;                // 0:Q 1:K 2:V
  const float* Wsrc = (mat == 0) ? Wq : ((mat == 1) ? Wk : Wv);
  const float* ga = x + (size_t)(m0 + ar) * EMB + aq * 16;
  const float* gb = Wsrc + (size_t)((n0 & 511) + br) * EMB + bh2 * 32;
  u16* la = &As[ar * LDB + aq * 16];
  u16* lb = &Bs[br * LDB + bh2 * 32];

  float4 pa0, pa1, pa2, pa3;
  float4 pb0, pb1, pb2, pb3, pb4, pb5, pb6, pb7;
  pa0 = *(const float4*)(ga);      pa1 = *(const float4*)(ga + 4);
  pa2 = *(const float4*)(ga + 8);  pa3 = *(const float4*)(ga + 12);
  pb0 = *(const float4*)(gb);      pb1 = *(const float4*)(gb + 4);
  pb2 = *(const float4*)(gb + 8);  pb3 = *(const float4*)(gb + 12);
  pb4 = *(const float4*)(gb + 16); pb5 = *(const float4*)(gb + 20);
  pb6 = *(const float4*)(gb + 24); pb7 = *(const float4*)(gb + 28);
  ga += 64; gb += 64;

  for (int k0 = 0; k0 < EMB; k0 += 64) {
    __syncthreads();
    *(u32x4*)(la)      = cvt4(pa0, pa1);
    *(u32x4*)(la + 8)  = cvt4(pa2, pa3);
    *(u32x4*)(lb)      = cvt4(pb0, pb1);
    *(u32x4*)(lb + 8)  = cvt4(pb2, pb3);
    *(u32x4*)(lb + 16) = cvt4(pb4, pb5);
    *(u32x4*)(lb + 24) = cvt4(pb6, pb7);
    __syncthreads();
    if (k0 + 64 < EMB) {
      pa0 = *(const float4*)(ga);      pa1 = *(const float4*)(ga + 4);
      pa2 = *(const float4*)(ga + 8);  pa3 = *(const float4*)(ga + 12);
      pb0 = *(const float4*)(gb);      pb1 = *(const float4*)(gb + 4);
      pb2 = *(const float4*)(gb + 8);  pb3 = *(const float4*)(gb + 12);
      pb4 = *(const float4*)(gb + 16); pb5 = *(const float4*)(gb + 20);
      pb6 = *(const float4*)(gb + 24); pb7 = *(const float4*)(gb + 28);
      ga += 64; gb += 64;
    }
    bf16x8 af[4][2], bfr[2][2];
    #pragma unroll
    for (int mi = 0; mi < 4; mi++)
      #pragma unroll
      for (int kk = 0; kk < 2; kk++)
        af[mi][kk] = ldfrag(&As[(mi*16 + l15) * LDB + kk*32 + q*8]);
    #pragma unroll
    for (int ni = 0; ni < 2; ni++)
      #pragma unroll
      for (int kk = 0; kk < 2; kk++)
        bfr[ni][kk] = ldfrag(&Bs[(w*32 + ni*16 + l15) * LDB + kk*32 + q*8]);
    #pragma unroll
    for (int mi = 0; mi < 4; mi++)
      #pragma unroll
      for (int ni = 0; ni < 2; ni++)
        #pragma unroll
        for (int kk = 0; kk < 2; kk++)
          acc[mi][ni] = MFMA16(af[mi][kk], bfr[ni][kk], acc[mi][ni]);
  }

  // -------- epilogue: LDS-staged, per-head coalesced stores (unchanged) ----
  const float* bias = (mat == 0) ? bq : ((mat == 1) ? bk : bv);
  const float mul = (mat == 0) ? 0.125f * L2E : 1.0f;
  const int b_ = m0 >> 11;
  const int nbase = m0 & 2047;

  #pragma unroll
  for (int p = 0; p < 2; p++) {           // one head per pass
    __syncthreads();
    if ((w >> 1) == p) {
      #pragma unroll
      for (int ni = 0; ni < 2; ni++) {
        const int dd = (w & 1) * 32 + ni * 16 + l15;
        const float bsv = bias[(n0 & 511) + (w * 32 + ni * 16 + l15)];
        #pragma unroll
        for (int mi = 0; mi < 4; mi++) {
          #pragma unroll
          for (int r = 0; r < 4; r++) {
            const int nr = mi * 16 + q * 4 + r;        // n rel. to nbase
            const float val = (acc[mi][ni][r] + bsv) * mul;
            int idx;
            if (mat == 0)      idx = nr * 64 + dd;
            else if (mat == 1) idx = (nr >> 4) * 1024 + ((dd >> 5) << 9)
                                   + ((((dd >> 3) & 3) * 16 + (nr & 15)) << 3) + (dd & 7);
            else               idx = ((dd >> 4) << 10) + (((nr >> 5) & 1) << 9)
                                   + ((((nr >> 3) & 3) * 16 + (dd & 15)) << 3) + (nr & 7);
            sm[idx] = f2bf(val);
          }
        }
      }
    }
    __syncthreads();
    const int hh = ((n0 & 511) >> 6) + p;
    u16* gdst;
    if (mat == 0)      gdst = qh  + ((size_t)(b_ * NH + hh) * SEQ + nbase) * HD;
    else if (mat == 1) gdst = ksw + (size_t)(b_ * NH + hh) * 131072 + (nbase >> 4) * 1024;
    else               gdst = vsw + (size_t)(b_ * NH + hh) * 131072 + (nbase >> 6) * 4096;
    *(u32x4*)(gdst + tid * 16)     = *(const u32x4*)(sm + tid * 16);
    *(u32x4*)(gdst + tid * 16 + 8) = *(const u32x4*)(sm + tid * 16 + 8);
  }
}

// ---------------------------------------------------------------- k3: out GEMM 64x64, BK=64
// A = (om0 + om1) * rl combined during staging; B staged from f32 Wo.
__global__ __launch_bounds__(256) void gemm_out_kernel(
    const u16* __restrict__ om0, const u16* __restrict__ om1,
    const float* __restrict__ lsp, const float* __restrict__ Wo,
    const float* __restrict__ bo, float* __restrict__ out)
{
  __shared__ u16 As[64 * LDB];
  __shared__ u16 Bs[64 * LDB];
  const int tid = threadIdx.x;
  const int lane = tid & 63, w = tid >> 6;
  const int q = lane >> 4, l15 = lane & 15;
  const int m0 = blockIdx.y * 64;
  const int n0 = blockIdx.x * 64;

  f32x4 acc[4];
  f32x4 zero = {0.f, 0.f, 0.f, 0.f};
  #pragma unroll
  for (int i = 0; i < 4; i++) acc[i] = zero;

  // staging map: A and B both 64 rows x 64 k -> 4 thr/row (16 elems each)
  const int ar = tid >> 2, aq = tid & 3;
  const int arow = m0 + ar;                 // b*2048 + n
  // lsum partial index: ((b*8 + h)*2048 + n); h = k0>>6 steps 0..7
  const int libase = (arow >> 11) * 16384 + (arow & 2047);
  const u16* ga0 = om0 + (size_t)arow * EMB + aq * 16;
  const u16* ga1 = om1 + (size_t)arow * EMB + aq * 16;
  const float* gbw = Wo + (size_t)(n0 + ar) * EMB + aq * 16;
  u16* la = &As[ar * LDB + aq * 16];
  u16* lb = &Bs[ar * LDB + aq * 16];

  u32x4 a0, a1, d0, d1;
  float4 pw0, pw1, pw2, pw3;
  float rl;
  a0 = *(const u32x4*)(ga0); a1 = *(const u32x4*)(ga0 + 8);
  d0 = *(const u32x4*)(ga1); d1 = *(const u32x4*)(ga1 + 8);
  pw0 = *(const float4*)(gbw);     pw1 = *(const float4*)(gbw + 4);
  pw2 = *(const float4*)(gbw + 8); pw3 = *(const float4*)(gbw + 12);
  rl = 1.0f / (lsp[libase] + lsp[32768 + libase]);
  ga0 += 64; ga1 += 64; gbw += 64;

  for (int k0 = 0; k0 < EMB; k0 += 64) {
    __syncthreads();
    *(u32x4*)(la)     = comb4(a0, d0, rl);
    *(u32x4*)(la + 8) = comb4(a1, d1, rl);
    *(u32x4*)(lb)     = cvt4(pw0, pw1);
    *(u32x4*)(lb + 8) = cvt4(pw2, pw3);
    __syncthreads();
    if (k0 + 64 < EMB) {
      const int h = (k0 + 64) >> 6;
      a0 = *(const u32x4*)(ga0); a1 = *(const u32x4*)(ga0 + 8);
      d0 = *(const u32x4*)(ga1); d1 = *(const u32x4*)(ga1 + 8);
      pw0 = *(const float4*)(gbw);     pw1 = *(const float4*)(gbw + 4);
      pw2 = *(const float4*)(gbw + 8); pw3 = *(const float4*)(gbw + 12);
      rl = 1.0f / (lsp[libase + h * 2048] + lsp[32768 + libase + h * 2048]);
      ga0 += 64; ga1 += 64; gbw += 64;
    }
    bf16x8 af[4][2], bfr[2];
    #pragma unroll
    for (int mi = 0; mi < 4; mi++)
      #pragma unroll
      for (int kk = 0; kk < 2; kk++)
        af[mi][kk] = ldfrag(&As[(mi*16 + l15) * LDB + kk*32 + q*8]);
    #pragma unroll
    for (int kk = 0; kk < 2; kk++)
      bfr[kk] = ldfrag(&Bs[(w*16 + l15) * LDB + kk*32 + q*8]);
    #pragma unroll
    for (int mi = 0; mi < 4; mi++)
      #pragma unroll
      for (int kk = 0; kk < 2; kk++)
        acc[mi] = MFMA16(af[mi][kk], bfr[kk], acc[mi]);
  }

  int col = n0 + w*16 + l15;
  float bsv = bo[col];
  #pragma unroll
  for (int mi = 0; mi < 4; mi++) {
    int rowb = m0 + mi*16 + q*4;
    #pragma unroll
    for (int r = 0; r < 4; r++)
      out[(size_t)(rowb + r) * EMB + col] = acc[mi][r] + bsv;
  }
}

// ---------------------------------------------------------------- k2: flash (r11 verbatim)
// 256 thr = 4 waves. Wave w: i-rows i0+w*16, j-tiles [jh*16, jh*16+16).
// K/V tiles staged once per block (glds, double-buffered). Frags via ds_read_b128.
// Output: unnormalized O partial (bf16) + lsum partial (f32); gemm_out combines.
template<int MT>
struct FlashCtx {
  const u16 *kgp, *vgp;        // (b,h) plane base, u16
  const float* arow;           // adjacency row base for this wave
  bf16x8 qf0, qf1;
  float Ah, Bh;
  float ctr[MT], dtr[MT], wtr[MT];
  int lane, w, q, l15, pxor;
};

template<int MT>
static __device__ __forceinline__ void flash_stage(const FlashCtx<MT>& c,
                                                   u16* Kb, u16* Vb, int it) {
  // wave w copies bytes [w*2048, w*2048+2048) of the 8KB tile, 2 glds each
  const int o = c.w * 1024 + c.lane * 8;   // u16 units
  const u16* kg = c.kgp + it * 4096;
  const u16* vg = c.vgp + it * 4096;
  glds16(kg + o,       Kb + o);
  glds16(kg + o + 512, Kb + o + 512);
  glds16(vg + o,       Vb + o);
  glds16(vg + o + 512, Vb + o + 512);
}

template<int MT>
static __device__ __forceinline__ void flash_iter(
    const FlashCtx<MT>& c, int it, int tend, u16* Kb, u16* Vb, u16* nKb, u16* nVb,
    u16* psw, float4* avc, float4* avn, f32x4* O, float& lsum)
{
  __syncthreads();                       // gates buf(it); drains glds(it) issued last iter
  if (it + 1 < tend) flash_stage(c, nKb, nVb, it + 1);
  const int nx = (it + 1 < tend) ? it + 1 : tend - 1;
  #pragma unroll
  for (int jt = 0; jt < 4; jt++)
    avn[jt] = *(const float4*)(c.arow + nx * 64 + jt * 16);
  __builtin_amdgcn_sched_barrier(0);     // keep prefetch above compute

  f32x4 zero = {0.f, 0.f, 0.f, 0.f};
  const int lo = c.lane * 8;

  // S^T = MFMA(kf, qf)
  f32x4 S[4];
  #pragma unroll
  for (int jt = 0; jt < 4; jt++) {
    bf16x8 kf0 = ldfrag(Kb + jt * 1024 + lo);
    bf16x8 kf1 = ldfrag(Kb + jt * 1024 + 512 + lo);
    f32x4 s = MFMA16(kf0, c.qf0, zero);
    S[jt] = MFMA16(kf1, c.qf1, s);
  }

  // halves: edge+exp+P-write for 2 jt, then P-read + 4 PV MFMAs
  #pragma unroll
  for (int half = 0; half < 2; half++) {
    #pragma unroll
    for (int jj = 0; jj < 2; jj++) {
      const int jt = half * 2 + jj;
      float p[4];
      #pragma unroll
      for (int r = 0; r < 4; r++) {
        float a = ((const float*)&avc[jt])[r];
        float e = fmaf(a, c.Bh, c.Ah);
        #pragma unroll
        for (int t = 0; t < MT; t++)
          e = fmaf(fabsf(fmaf(a, c.ctr[t], c.dtr[t])), c.wtr[t], e);
        p[r] = __builtin_amdgcn_exp2f(S[jt][r] + e);
        lsum += p[r];
      }
      *(uint2*)(psw + ((c.l15 * 64 + jt * 16 + c.q * 4) ^ c.pxor)) =
          make_uint2(pack2(p[0], p[1]), pack2(p[2], p[3]));
    }
    bf16x8 pf = ldfrag(psw + ((c.l15 * 64 + half * 32 + c.q * 8) ^ c.pxor));
    #pragma unroll
    for (int dt = 0; dt < 4; dt++) {
      bf16x8 vf = ldfrag(Vb + dt * 1024 + half * 512 + lo);
      O[dt] = MFMA16(vf, pf, O[dt]);
    }
  }
}

template<int MT>
__device__ __forceinline__ void flash_body(
    u16* Kb0, u16* Kb1, u16* Vb0, u16* Vb1, u16* Pb,
    const u16* __restrict__ qh, const u16* __restrict__ ksw, const u16* __restrict__ vsw,
    const float* __restrict__ adj, const float* __restrict__ coeff,
    u16* __restrict__ om0, u16* __restrict__ om1, float* __restrict__ lsp)
{
  const int tid = threadIdx.x, lane = tid & 63, w = tid >> 6;
  const int q = lane >> 4, l15 = lane & 15;
  const int i0 = blockIdx.x * 64;
  const int h = blockIdx.y;
  const int b = blockIdx.z >> 1, jh = blockIdx.z & 1;
  const int t0 = jh * 16, tend = t0 + 16;
  const int bh = b * NH + h;
  const int iw = i0 + w * 16;

  FlashCtx<MT> c;
  c.lane = lane; c.w = w; c.q = q; c.l15 = l15;
  c.pxor = (l15 & 7) << 3;
  c.Ah = coeff[h]; c.Bh = coeff[8 + h];
  #pragma unroll
  for (int t = 0; t < MT; t++) {
    c.ctr[t] = coeff[17 + t];
    c.dtr[t] = coeff[33 + t];
    c.wtr[t] = coeff[49 + t * 8 + h];
  }
  const u16* qrow = qh + ((size_t)bh * SEQ + iw + l15) * HD;
  c.qf0 = ldfrag(qrow + q * 8);
  c.qf1 = ldfrag(qrow + 32 + q * 8);
  c.kgp = ksw + (size_t)bh * 131072;
  c.vgp = vsw + (size_t)bh * 131072;
  c.arow = adj + ((size_t)b * SEQ + iw + l15) * SEQ + q * 4;

  f32x4 O[4];
  f32x4 zero = {0.f, 0.f, 0.f, 0.f};
  #pragma unroll
  for (int dt = 0; dt < 4; dt++) O[dt] = zero;
  float lsum = 0.0f;

  u16* psw = Pb + w * 1024;   // 16*64 per wave (XOR-swizzled)

  // prologue: stage first tile + adjacency
  flash_stage(c, Kb0, Vb0, t0);
  float4 avA[4], avB[4];
  #pragma unroll
  for (int jt = 0; jt < 4; jt++)
    avA[jt] = *(const float4*)(c.arow + t0 * 64 + jt * 16);

  #pragma unroll 1
  for (int it2 = t0; it2 < tend; it2 += 2) {
    flash_iter(c, it2,     tend, Kb0, Vb0, Kb1, Vb1, psw, avA, avB, O, lsum);
    flash_iter(c, it2 + 1, tend, Kb1, Vb1, Kb0, Vb0, psw, avB, avA, O, lsum);
  }

  // partial row-sum for i=l15 (reduce across the 4 quads), store f32
  lsum += __shfl_xor(lsum, 16);
  lsum += __shfl_xor(lsum, 32);
  if (lane < 16)
    lsp[(size_t)jh * 32768 + (size_t)bh * SEQ + iw + l15] = lsum;

  // unnormalized partial O in bf16
  u16* orow = (jh ? om1 : om0)
            + ((size_t)b * SEQ + iw + l15) * EMB + h * HD + q * 4;
  #pragma unroll
  for (int dt = 0; dt < 4; dt++)
    *(uint2*)(orow + dt * 16) = make_uint2(pack2(O[dt][0], O[dt][1]),
                                           pack2(O[dt][2], O[dt][3]));
}

__global__ __launch_bounds__(256, 4) void flash_kernel(
    const u16* __restrict__ qh, const u16* __restrict__ ksw, const u16* __restrict__ vsw,
    const float* __restrict__ adj, const float* __restrict__ coeff,
    u16* __restrict__ om0, u16* __restrict__ om1, float* __restrict__ lsp)
{
  __shared__ __align__(16) u16 Kb[2][4096];   // 16 KB
  __shared__ __align__(16) u16 Vb[2][4096];   // 16 KB
  __shared__ __align__(16) u16 Pb[4096];      //  8 KB  (total 40960 = 4 blocks/CU)
  const int mt = ((const int*)coeff)[16];
  if (mt <= 4)
    flash_body<4>(Kb[0], Kb[1], Vb[0], Vb[1], Pb, qh, ksw, vsw, adj, coeff, om0, om1, lsp);
  else if (mt <= 8)
    flash_body<8>(Kb[0], Kb[1], Vb[0], Vb[1], Pb, qh, ksw, vsw, adj, coeff, om0, om1, lsp);
  else
    flash_body<16>(Kb[0], Kb[1], Vb[0], Vb[1], Pb, qh, ksw, vsw, adj, coeff, om0, om1, lsp);
}

// ---------------------------------------------------------------- launch
extern "C" void kernel_launch(void* const* d_in, const int* in_sizes, int n_in,
                              void* d_out, int out_size, void* d_ws, size_t ws_size,
                              hipStream_t stream) {
  const float* x     = (const float*)d_in[0];
  const float* adj   = (const float*)d_in[1];
  const float* Wq    = (const float*)d_in[2];
  const float* bq    = (const float*)d_in[3];
  const float* Wk    = (const float*)d_in[4];
  const float* bk    = (const float*)d_in[5];
  const float* Wv    = (const float*)d_in[6];
  const float* bv    = (const float*)d_in[7];
  const float* Wo    = (const float*)d_in[8];
  const float* bo    = (const float*)d_in[9];
  const float* We1   = (const float*)d_in[10];
  const float* be1   = (const float*)d_in[11];
  const float* We2   = (const float*)d_in[12];
  const float* be2   = (const float*)d_in[13];
  const float* ebias = (const float*)d_in[14];
  float* out = (float*)d_out;

  char* ws = (char*)d_ws;
  u16*   om1  = (u16*)(ws + 0);          //  4 MB  partial jh=1
  float* lsp  = (float*)(ws + 4194304);  //  256KB lsum partials
  u16*   qh   = (u16*)(ws + 6291456);    //  4 MB  (B,H,N,64) row-major
  u16*   ksw  = (u16*)(ws + 10485760);   //  4 MB  fragment-major K
  u16*   vsw  = (u16*)(ws + 14680064);   //  4 MB  fragment-major V
  u16*   om0  = (u16*)(ws + 18874368);   //  4 MB  partial jh=0 (B,N,512) bf16
  float* co   = (float*)(ws + 23068672); //  1 KB  edge coefficients
  if (ws_size < 23069696) return;

  gemm_qkv_kernel<<<dim3(12, 64), 256, 0, stream>>>(
      x, Wq, Wk, Wv, bq, bk, bv, We1, be1, We2, be2, ebias, qh, ksw, vsw, co);
  flash_kernel<<<dim3(32, NH, NB * 2), 256, 0, stream>>>(qh, ksw, vsw, adj, co,
                                                         om0, om1, lsp);
  gemm_out_kernel<<<dim3(8, 64), 256, 0, stream>>>(om0, om1, lsp, Wo, bo, out);
}

// Round 7
// 184.513 us; speedup vs baseline: 1.1082x; 1.1082x over previous
//
#include <hip/hip_runtime.h>
#include <stdint.h>

// EdgeAwareMultiHeadAttention on MI355X (gfx950) — round 13
// Changes vs round 12:
//  * PIPELINE REVERTED to round-11 (best total 185.2us): prep_kernel restored,
//    bf16-staged GEMMs, combine folded in gemm_out. r12's f32-staging fold
//    cost +15-20us in the GEMMs (2x staging bytes + cvt in hot loop) and the
//    launch-count reduction saved nothing -> launch-overhead theory dead.
//  * flash: edge-MLP rewritten in PACKED f32 (f32x2 elementwise fma/max ->
//    v_pk_fma_f32 / v_pk_max_f32 with neg modifier). The per-element chain
//    1+3*MT scalar FMA-class ops (~25-28us of pure VALU across the kernel,
//    matching VALUBusy 47% x 60.5us) halves in instruction count.
//    max(u,-u) == fabs(u) for finite u; fma rounding identical -> absmax
//    unchanged. MT=16 path stays scalar (mt~4 expected; template fallback).
//  * Everything else identical to r11.

#define SEQ 2048
#define EMB 512
#define NH  8
#define HD  64
#define NB  2
#define L2E 1.4426950408889634f

typedef unsigned int   u32;
typedef unsigned short u16;
typedef u32   u32x4  __attribute__((ext_vector_type(4)));
typedef float f32x4  __attribute__((ext_vector_type(4)));
typedef float f32x2  __attribute__((ext_vector_type(2)));
typedef __bf16 bf16x8 __attribute__((ext_vector_type(8)));

#define MFMA16(a, b, c) __builtin_amdgcn_mfma_f32_16x16x32_bf16((a), (b), (c), 0, 0, 0)

static __device__ __forceinline__ u16 f2bf(float f) {
  return __builtin_bit_cast(u16, (__bf16)f);
}
static __device__ __forceinline__ u32 pack2(float a, float b) {
  return (u32)f2bf(a) | ((u32)f2bf(b) << 16);
}
static __device__ __forceinline__ bf16x8 ldfrag(const u16* p) {
  return __builtin_bit_cast(bf16x8, *(const u32x4*)p);
}
// async global->LDS, 16B per lane (dst = wave-uniform base + lane*16)
static __device__ __forceinline__ void glds16(const u16* g, u16* l) {
  __builtin_amdgcn_global_load_lds(
      (const __attribute__((address_space(1))) u32*)(const void*)g,
      (__attribute__((address_space(3))) u32*)(void*)l, 16, 0, 0);
}
// combine two bf16 pairs with scale: (bf(a)+bf(d))*rl, repacked to bf16x2
static __device__ __forceinline__ u32 comb2(u32 a, u32 d, float rl) {
  float lo = __builtin_bit_cast(float, a << 16)
           + __builtin_bit_cast(float, d << 16);
  float hi = __builtin_bit_cast(float, a & 0xffff0000u)
           + __builtin_bit_cast(float, d & 0xffff0000u);
  return pack2(lo * rl, hi * rl);
}
static __device__ __forceinline__ u32x4 comb4(u32x4 a, u32x4 d, float rl) {
  u32x4 r;
  r[0] = comb2(a[0], d[0], rl); r[1] = comb2(a[1], d[1], rl);
  r[2] = comb2(a[2], d[2], rl); r[3] = comb2(a[3], d[3], rl);
  return r;
}

// Fragment-major layouts, per (b,h) plane of 131072 u16 (2048x64):
//  ksw: (n,d) -> (n>>4)*1024 + (d>>5)*512 + (((d>>3)&3)*16 + (n&15))*8 + (d&7)
//  vsw: (n,d) -> (n>>6)*4096 + (d>>4)*1024 + ((n>>5)&1)*512
//               + (((n>>3)&3)*16 + (d&15))*8 + (n&7)
// One 64-j tile = 4096 u16 contiguous -> LDS image is a straight copy.

// ---------------------------------------------------------------- prep
__global__ void prep_kernel(const float* __restrict__ x,
                            const float* __restrict__ Wq, const float* __restrict__ Wk,
                            const float* __restrict__ Wv, const float* __restrict__ Wo,
                            const float* __restrict__ We1, const float* __restrict__ be1,
                            const float* __restrict__ We2, const float* __restrict__ be2,
                            const float* __restrict__ ebias,
                            u16* __restrict__ xb, u16* __restrict__ wqkv,
                            u16* __restrict__ wob, float* __restrict__ co) {
  const int blk = blockIdx.x, tid = threadIdx.x;
  if (blk < 2048) {
    int i = (blk * 256 + tid) * 4;
    float4 v = *(const float4*)(x + i);
    *(uint2*)(xb + i) = make_uint2(pack2(v.x, v.y), pack2(v.z, v.w));
  } else if (blk < 3072) {
    int i = ((blk - 2048) * 256 + tid) * 4;
    int m = i >> 18;
    int off = i & 262143;
    const float* src = (m == 0) ? Wq : ((m == 1) ? Wk : ((m == 2) ? Wv : Wo));
    u16* dst = (m < 3) ? (wqkv + (size_t)m * 262144) : wob;
    float4 v = *(const float4*)(src + off);
    *(uint2*)(dst + off) = make_uint2(pack2(v.x, v.y), pack2(v.z, v.w));
  } else {
    const int e = tid & 15, h = tid >> 4;
    if (tid < 128) {
      co[49 + e * 8 + h] = 0.0f;
      if (h == 0) { co[17 + e] = 0.0f; co[33 + e] = 0.0f; }
    }
    __syncthreads();
    if (tid < 128) {
      float w1 = We1[e], b1 = be1[e], w2 = We2[h * 16 + e];
      float u0 = b1, u1 = w1 + b1;
      bool on  = (u0 >= 0.0f) && (u1 >= 0.0f);
      bool off = (u0 <= 0.0f) && (u1 <= 0.0f);
      bool crossing = (!on) && (!off);
      float ca = on ? (w2 * b1) : (crossing ? 0.5f * w2 * b1 : 0.0f);
      float cb = on ? (w2 * w1) : (crossing ? 0.5f * w2 * w1 : 0.0f);
      #pragma unroll
      for (int d = 1; d < 16; d <<= 1) { ca += __shfl_xor(ca, d); cb += __shfl_xor(cb, d); }
      if (e == 0) { co[h] = (be2[h] + ca) * L2E; co[8 + h] = (ebias[h] + cb) * L2E; }
      unsigned long long msk = __ballot(crossing);
      int midx = __popcll(msk & 0xFFFFull & ((1ull << e) - 1ull));
      int mcnt = __popcll(msk & 0xFFFFull);
      if (crossing) {
        co[49 + midx * 8 + h] = 0.5f * w2 * L2E;
        if (h == 0) { co[17 + midx] = w1; co[33 + midx] = b1; }
      }
      if (tid == 0) ((int*)co)[16] = mcnt;
    }
  }
}

// ---------------------------------------------------------------- k1: QKV GEMM 64x128, BK=64
#define LDB 72
__global__ __launch_bounds__(256) void gemm_qkv_kernel(
    const u16* __restrict__ A, const u16* __restrict__ Bm,
    const float* __restrict__ bq, const float* __restrict__ bk, const float* __restrict__ bv,
    u16* __restrict__ qh, u16* __restrict__ ksw, u16* __restrict__ vsw)
{
  __shared__ u16 sm[64 * LDB + 128 * LDB];   // As | Bs (27.6KB), reused by epilogue
  u16* As = sm;
  u16* Bs = sm + 64 * LDB;
  const int tid = threadIdx.x;
  const int lane = tid & 63, w = tid >> 6;
  const int q = lane >> 4, l15 = lane & 15;
  const int m0 = blockIdx.y * 64;
  const int n0 = blockIdx.x * 128;

  f32x4 acc[4][2];
  f32x4 zero = {0.f, 0.f, 0.f, 0.f};
  #pragma unroll
  for (int i = 0; i < 4; i++) { acc[i][0] = zero; acc[i][1] = zero; }

  // staging map: A 64 rows x 64 k -> 4 thr/row (16 u16 each);
  //              B 128 rows x 64 k -> 2 thr/row (32 u16 each)
  const int ar = tid >> 2, aq = tid & 3;
  const int br = tid >> 1, bh = tid & 1;
  const u16* ga = A  + (size_t)(m0 + ar) * EMB + aq * 16;
  const u16* gb = Bm + (size_t)(n0 + br) * EMB + bh * 32;
  u16* la = &As[ar * LDB + aq * 16];
  u16* lb = &Bs[br * LDB + bh * 32];

  u32x4 a0, a1, b0, b1, b2, b3;
  a0 = *(const u32x4*)(ga);      a1 = *(const u32x4*)(ga + 8);
  b0 = *(const u32x4*)(gb);      b1 = *(const u32x4*)(gb + 8);
  b2 = *(const u32x4*)(gb + 16); b3 = *(const u32x4*)(gb + 24);
  ga += 64; gb += 64;

  for (int k0 = 0; k0 < EMB; k0 += 64) {
    __syncthreads();
    *(u32x4*)(la) = a0;      *(u32x4*)(la + 8) = a1;
    *(u32x4*)(lb) = b0;      *(u32x4*)(lb + 8) = b1;
    *(u32x4*)(lb + 16) = b2; *(u32x4*)(lb + 24) = b3;
    __syncthreads();
    if (k0 + 64 < EMB) {
      a0 = *(const u32x4*)(ga);      a1 = *(const u32x4*)(ga + 8);
      b0 = *(const u32x4*)(gb);      b1 = *(const u32x4*)(gb + 8);
      b2 = *(const u32x4*)(gb + 16); b3 = *(const u32x4*)(gb + 24);
      ga += 64; gb += 64;
    }
    bf16x8 af[4][2], bfr[2][2];
    #pragma unroll
    for (int mi = 0; mi < 4; mi++)
      #pragma unroll
      for (int kk = 0; kk < 2; kk++)
        af[mi][kk] = ldfrag(&As[(mi*16 + l15) * LDB + kk*32 + q*8]);
    #pragma unroll
    for (int ni = 0; ni < 2; ni++)
      #pragma unroll
      for (int kk = 0; kk < 2; kk++)
        bfr[ni][kk] = ldfrag(&Bs[(w*32 + ni*16 + l15) * LDB + kk*32 + q*8]);
    #pragma unroll
    for (int mi = 0; mi < 4; mi++)
      #pragma unroll
      for (int ni = 0; ni < 2; ni++)
        #pragma unroll
        for (int kk = 0; kk < 2; kk++)
          acc[mi][ni] = MFMA16(af[mi][kk], bfr[ni][kk], acc[mi][ni]);
  }

  // -------- epilogue: LDS-staged, per-head coalesced stores --------
  const int mat = n0 >> 9;                // 0:Q 1:K 2:V
  const float* bias = (mat == 0) ? bq : ((mat == 1) ? bk : bv);
  const float mul = (mat == 0) ? 0.125f * L2E : 1.0f;
  const int b_ = m0 >> 11;
  const int nbase = m0 & 2047;

  #pragma unroll
  for (int p = 0; p < 2; p++) {           // one head per pass
    __syncthreads();
    if ((w >> 1) == p) {
      #pragma unroll
      for (int ni = 0; ni < 2; ni++) {
        const int dd = (w & 1) * 32 + ni * 16 + l15;
        const float bsv = bias[(n0 & 511) + (w * 32 + ni * 16 + l15)];
        #pragma unroll
        for (int mi = 0; mi < 4; mi++) {
          #pragma unroll
          for (int r = 0; r < 4; r++) {
            const int nr = mi * 16 + q * 4 + r;        // n rel. to nbase
            const float val = (acc[mi][ni][r] + bsv) * mul;
            int idx;
            if (mat == 0)      idx = nr * 64 + dd;
            else if (mat == 1) idx = (nr >> 4) * 1024 + ((dd >> 5) << 9)
                                   + ((((dd >> 3) & 3) * 16 + (nr & 15)) << 3) + (dd & 7);
            else               idx = ((dd >> 4) << 10) + (((nr >> 5) & 1) << 9)
                                   + ((((nr >> 3) & 3) * 16 + (dd & 15)) << 3) + (nr & 7);
            sm[idx] = f2bf(val);
          }
        }
      }
    }
    __syncthreads();
    const int hh = ((n0 & 511) >> 6) + p;
    u16* gdst;
    if (mat == 0)      gdst = qh  + ((size_t)(b_ * NH + hh) * SEQ + nbase) * HD;
    else if (mat == 1) gdst = ksw + (size_t)(b_ * NH + hh) * 131072 + (nbase >> 4) * 1024;
    else               gdst = vsw + (size_t)(b_ * NH + hh) * 131072 + (nbase >> 6) * 4096;
    *(u32x4*)(gdst + tid * 16)     = *(const u32x4*)(sm + tid * 16);
    *(u32x4*)(gdst + tid * 16 + 8) = *(const u32x4*)(sm + tid * 16 + 8);
  }
}

// ---------------------------------------------------------------- k3: out GEMM 64x64, BK=64
// A = (om0 + om1) * rl combined during staging (folds combine_kernel).
__global__ __launch_bounds__(256) void gemm_out_kernel(
    const u16* __restrict__ om0, const u16* __restrict__ om1,
    const float* __restrict__ lsp, const u16* __restrict__ Bm,
    const float* __restrict__ bo, float* __restrict__ out)
{
  __shared__ u16 As[64 * LDB];
  __shared__ u16 Bs[64 * LDB];
  const int tid = threadIdx.x;
  const int lane = tid & 63, w = tid >> 6;
  const int q = lane >> 4, l15 = lane & 15;
  const int m0 = blockIdx.y * 64;
  const int n0 = blockIdx.x * 64;

  f32x4 acc[4];
  f32x4 zero = {0.f, 0.f, 0.f, 0.f};
  #pragma unroll
  for (int i = 0; i < 4; i++) acc[i] = zero;

  // staging map: A and B both 64 rows x 64 k -> 4 thr/row (16 u16 each)
  const int ar = tid >> 2, aq = tid & 3;
  const int arow = m0 + ar;                 // b*2048 + n
  // lsum partial index: ((b*8 + h)*2048 + n); h = k0>>6 steps 0..7
  const int libase = (arow >> 11) * 16384 + (arow & 2047);
  const u16* ga0 = om0 + (size_t)arow * EMB + aq * 16;
  const u16* ga1 = om1 + (size_t)arow * EMB + aq * 16;
  const u16* gb  = Bm + (size_t)(n0 + ar) * EMB + aq * 16;
  u16* la = &As[ar * LDB + aq * 16];
  u16* lb = &Bs[ar * LDB + aq * 16];

  u32x4 a0, a1, d0, d1, b0, b1;
  float rl;
  a0 = *(const u32x4*)(ga0); a1 = *(const u32x4*)(ga0 + 8);
  d0 = *(const u32x4*)(ga1); d1 = *(const u32x4*)(ga1 + 8);
  b0 = *(const u32x4*)(gb);  b1 = *(const u32x4*)(gb + 8);
  rl = 1.0f / (lsp[libase] + lsp[32768 + libase]);
  ga0 += 64; ga1 += 64; gb += 64;

  for (int k0 = 0; k0 < EMB; k0 += 64) {
    __syncthreads();
    *(u32x4*)(la)     = comb4(a0, d0, rl);
    *(u32x4*)(la + 8) = comb4(a1, d1, rl);
    *(u32x4*)(lb) = b0; *(u32x4*)(lb + 8) = b1;
    __syncthreads();
    if (k0 + 64 < EMB) {
      const int h = (k0 + 64) >> 6;
      a0 = *(const u32x4*)(ga0); a1 = *(const u32x4*)(ga0 + 8);
      d0 = *(const u32x4*)(ga1); d1 = *(const u32x4*)(ga1 + 8);
      b0 = *(const u32x4*)(gb);  b1 = *(const u32x4*)(gb + 8);
      rl = 1.0f / (lsp[libase + h * 2048] + lsp[32768 + libase + h * 2048]);
      ga0 += 64; ga1 += 64; gb += 64;
    }
    bf16x8 af[4][2], bfr[2];
    #pragma unroll
    for (int mi = 0; mi < 4; mi++)
      #pragma unroll
      for (int kk = 0; kk < 2; kk++)
        af[mi][kk] = ldfrag(&As[(mi*16 + l15) * LDB + kk*32 + q*8]);
    #pragma unroll
    for (int kk = 0; kk < 2; kk++)
      bfr[kk] = ldfrag(&Bs[(w*16 + l15) * LDB + kk*32 + q*8]);
    #pragma unroll
    for (int mi = 0; mi < 4; mi++)
      #pragma unroll
      for (int kk = 0; kk < 2; kk++)
        acc[mi] = MFMA16(af[mi][kk], bfr[kk], acc[mi]);
  }

  int col = n0 + w*16 + l15;
  float bsv = bo[col];
  #pragma unroll
  for (int mi = 0; mi < 4; mi++) {
    int rowb = m0 + mi*16 + q*4;
    #pragma unroll
    for (int r = 0; r < 4; r++)
      out[(size_t)(rowb + r) * EMB + col] = acc[mi][r] + bsv;
  }
}

// ---------------------------------------------------------------- k2: flash (packed edge math)
// 256 thr = 4 waves. Wave w: i-rows i0+w*16, j-tiles [jh*16, jh*16+16).
// K/V tiles staged once per block (glds, double-buffered). Frags via ds_read_b128.
// Edge-MLP in packed f32 pairs (v_pk_fma/v_pk_max) for MT<=8.
// Output: unnormalized O partial (bf16) + lsum partial (f32); gemm_out combines.
template<int MT>
struct FlashCtx {
  const u16 *kgp, *vgp;        // (b,h) plane base, u16
  const float* arow;           // adjacency row base for this wave
  bf16x8 qf0, qf1;
  float Ah, Bh;                // scalar path (MT=16)
  f32x2 Ah2, Bh2;              // packed path (MT<=8)
  float ctr[(MT > 8) ? MT : 1], dtr[(MT > 8) ? MT : 1], wtr[(MT > 8) ? MT : 1];
  f32x2 ctr2[(MT <= 8) ? MT : 1], dtr2[(MT <= 8) ? MT : 1], wtr2[(MT <= 8) ? MT : 1];
  int lane, w, q, l15, pxor;
};

template<int MT>
static __device__ __forceinline__ void flash_stage(const FlashCtx<MT>& c,
                                                   u16* Kb, u16* Vb, int it) {
  // wave w copies bytes [w*2048, w*2048+2048) of the 8KB tile, 2 glds each
  const int o = c.w * 1024 + c.lane * 8;   // u16 units
  const u16* kg = c.kgp + it * 4096;
  const u16* vg = c.vgp + it * 4096;
  glds16(kg + o,       Kb + o);
  glds16(kg + o + 512, Kb + o + 512);
  glds16(vg + o,       Vb + o);
  glds16(vg + o + 512, Vb + o + 512);
}

template<int MT>
static __device__ __forceinline__ void flash_iter(
    const FlashCtx<MT>& c, int it, int tend, u16* Kb, u16* Vb, u16* nKb, u16* nVb,
    u16* psw, float4* avc, float4* avn, f32x4* O, float& lsum)
{
  __syncthreads();                       // gates buf(it); drains glds(it) issued last iter
  if (it + 1 < tend) flash_stage(c, nKb, nVb, it + 1);
  const int nx = (it + 1 < tend) ? it + 1 : tend - 1;
  #pragma unroll
  for (int jt = 0; jt < 4; jt++)
    avn[jt] = *(const float4*)(c.arow + nx * 64 + jt * 16);
  __builtin_amdgcn_sched_barrier(0);     // keep prefetch above compute

  f32x4 zero = {0.f, 0.f, 0.f, 0.f};
  const int lo = c.lane * 8;

  // S^T = MFMA(kf, qf)
  f32x4 S[4];
  #pragma unroll
  for (int jt = 0; jt < 4; jt++) {
    bf16x8 kf0 = ldfrag(Kb + jt * 1024 + lo);
    bf16x8 kf1 = ldfrag(Kb + jt * 1024 + 512 + lo);
    f32x4 s = MFMA16(kf0, c.qf0, zero);
    S[jt] = MFMA16(kf1, c.qf1, s);
  }

  // halves: edge+exp+P-write for 2 jt, then P-read + 4 PV MFMAs
  #pragma unroll
  for (int half = 0; half < 2; half++) {
    #pragma unroll
    for (int jj = 0; jj < 2; jj++) {
      const int jt = half * 2 + jj;
      float p[4];
      if constexpr (MT <= 8) {
        // packed f32 pairs: v_pk_fma_f32 + v_pk_max_f32(u, -u) == |u|
        const float* av = (const float*)&avc[jt];
        f32x2 a01 = {av[0], av[1]};
        f32x2 a23 = {av[2], av[3]};
        f32x2 e01 = __builtin_elementwise_fma(a01, c.Bh2, c.Ah2);
        f32x2 e23 = __builtin_elementwise_fma(a23, c.Bh2, c.Ah2);
        #pragma unroll
        for (int t = 0; t < MT; t++) {
          f32x2 u01 = __builtin_elementwise_fma(a01, c.ctr2[t], c.dtr2[t]);
          f32x2 u23 = __builtin_elementwise_fma(a23, c.ctr2[t], c.dtr2[t]);
          u01 = __builtin_elementwise_max(u01, -u01);
          u23 = __builtin_elementwise_max(u23, -u23);
          e01 = __builtin_elementwise_fma(u01, c.wtr2[t], e01);
          e23 = __builtin_elementwise_fma(u23, c.wtr2[t], e23);
        }
        f32x2 s01 = {S[jt][0], S[jt][1]};
        f32x2 s23 = {S[jt][2], S[jt][3]};
        s01 += e01; s23 += e23;
        p[0] = __builtin_amdgcn_exp2f(s01.x);
        p[1] = __builtin_amdgcn_exp2f(s01.y);
        p[2] = __builtin_amdgcn_exp2f(s23.x);
        p[3] = __builtin_amdgcn_exp2f(s23.y);
      } else {
        #pragma unroll
        for (int r = 0; r < 4; r++) {
          float a = ((const float*)&avc[jt])[r];
          float e = fmaf(a, c.Bh, c.Ah);
          #pragma unroll
          for (int t = 0; t < MT; t++)
            e = fmaf(fabsf(fmaf(a, c.ctr[t], c.dtr[t])), c.wtr[t], e);
          p[r] = __builtin_amdgcn_exp2f(S[jt][r] + e);
        }
      }
      lsum += (p[0] + p[1]) + (p[2] + p[3]);
      *(uint2*)(psw + ((c.l15 * 64 + jt * 16 + c.q * 4) ^ c.pxor)) =
          make_uint2(pack2(p[0], p[1]), pack2(p[2], p[3]));
    }
    bf16x8 pf = ldfrag(psw + ((c.l15 * 64 + half * 32 + c.q * 8) ^ c.pxor));
    #pragma unroll
    for (int dt = 0; dt < 4; dt++) {
      bf16x8 vf = ldfrag(Vb + dt * 1024 + half * 512 + lo);
      O[dt] = MFMA16(vf, pf, O[dt]);
    }
  }
}

template<int MT>
__device__ __forceinline__ void flash_body(
    u16* Kb0, u16* Kb1, u16* Vb0, u16* Vb1, u16* Pb,
    const u16* __restrict__ qh, const u16* __restrict__ ksw, const u16* __restrict__ vsw,
    const float* __restrict__ adj, const float* __restrict__ coeff,
    u16* __restrict__ om0, u16* __restrict__ om1, float* __restrict__ lsp)
{
  const int tid = threadIdx.x, lane = tid & 63, w = tid >> 6;
  const int q = lane >> 4, l15 = lane & 15;
  const int i0 = blockIdx.x * 64;
  const int h = blockIdx.y;
  const int b = blockIdx.z >> 1, jh = blockIdx.z & 1;
  const int t0 = jh * 16, tend = t0 + 16;
  const int bh = b * NH + h;
  const int iw = i0 + w * 16;

  FlashCtx<MT> c;
  c.lane = lane; c.w = w; c.q = q; c.l15 = l15;
  c.pxor = (l15 & 7) << 3;
  if constexpr (MT <= 8) {
    c.Ah2 = (f32x2){coeff[h], coeff[h]};
    c.Bh2 = (f32x2){coeff[8 + h], coeff[8 + h]};
    #pragma unroll
    for (int t = 0; t < MT; t++) {
      float cv = coeff[17 + t], dv = coeff[33 + t], wv = coeff[49 + t * 8 + h];
      c.ctr2[t] = (f32x2){cv, cv};
      c.dtr2[t] = (f32x2){dv, dv};
      c.wtr2[t] = (f32x2){wv, wv};
    }
  } else {
    c.Ah = coeff[h]; c.Bh = coeff[8 + h];
    #pragma unroll
    for (int t = 0; t < MT; t++) {
      c.ctr[t] = coeff[17 + t];
      c.dtr[t] = coeff[33 + t];
      c.wtr[t] = coeff[49 + t * 8 + h];
    }
  }
  const u16* qrow = qh + ((size_t)bh * SEQ + iw + l15) * HD;
  c.qf0 = ldfrag(qrow + q * 8);
  c.qf1 = ldfrag(qrow + 32 + q * 8);
  c.kgp = ksw + (size_t)bh * 131072;
  c.vgp = vsw + (size_t)bh * 131072;
  c.arow = adj + ((size_t)b * SEQ + iw + l15) * SEQ + q * 4;

  f32x4 O[4];
  f32x4 zero = {0.f, 0.f, 0.f, 0.f};
  #pragma unroll
  for (int dt = 0; dt < 4; dt++) O[dt] = zero;
  float lsum = 0.0f;

  u16* psw = Pb + w * 1024;   // 16*64 per wave (XOR-swizzled)

  // prologue: stage first tile + adjacency
  flash_stage(c, Kb0, Vb0, t0);
  float4 avA[4], avB[4];
  #pragma unroll
  for (int jt = 0; jt < 4; jt++)
    avA[jt] = *(const float4*)(c.arow + t0 * 64 + jt * 16);

  #pragma unroll 1
  for (int it2 = t0; it2 < tend; it2 += 2) {
    flash_iter(c, it2,     tend, Kb0, Vb0, Kb1, Vb1, psw, avA, avB, O, lsum);
    flash_iter(c, it2 + 1, tend, Kb1, Vb1, Kb0, Vb0, psw, avB, avA, O, lsum);
  }

  // partial row-sum for i=l15 (reduce across the 4 quads), store f32
  lsum += __shfl_xor(lsum, 16);
  lsum += __shfl_xor(lsum, 32);
  if (lane < 16)
    lsp[(size_t)jh * 32768 + (size_t)bh * SEQ + iw + l15] = lsum;

  // unnormalized partial O in bf16
  u16* orow = (jh ? om1 : om0)
            + ((size_t)b * SEQ + iw + l15) * EMB + h * HD + q * 4;
  #pragma unroll
  for (int dt = 0; dt < 4; dt++)
    *(uint2*)(orow + dt * 16) = make_uint2(pack2(O[dt][0], O[dt][1]),
                                           pack2(O[dt][2], O[dt][3]));
}

__global__ __launch_bounds__(256, 4) void flash_kernel(
    const u16* __restrict__ qh, const u16* __restrict__ ksw, const u16* __restrict__ vsw,
    const float* __restrict__ adj, const float* __restrict__ coeff,
    u16* __restrict__ om0, u16* __restrict__ om1, float* __restrict__ lsp)
{
  __shared__ __align__(16) u16 Kb[2][4096];   // 16 KB
  __shared__ __align__(16) u16 Vb[2][4096];   // 16 KB
  __shared__ __align__(16) u16 Pb[4096];      //  8 KB  (total 40960 = 4 blocks/CU)
  const int mt = ((const int*)coeff)[16];
  if (mt <= 4)
    flash_body<4>(Kb[0], Kb[1], Vb[0], Vb[1], Pb, qh, ksw, vsw, adj, coeff, om0, om1, lsp);
  else if (mt <= 8)
    flash_body<8>(Kb[0], Kb[1], Vb[0], Vb[1], Pb, qh, ksw, vsw, adj, coeff, om0, om1, lsp);
  else
    flash_body<16>(Kb[0], Kb[1], Vb[0], Vb[1], Pb, qh, ksw, vsw, adj, coeff, om0, om1, lsp);
}

// ---------------------------------------------------------------- launch
extern "C" void kernel_launch(void* const* d_in, const int* in_sizes, int n_in,
                              void* d_out, int out_size, void* d_ws, size_t ws_size,
                              hipStream_t stream) {
  const float* x     = (const float*)d_in[0];
  const float* adj   = (const float*)d_in[1];
  const float* Wq    = (const float*)d_in[2];
  const float* bq    = (const float*)d_in[3];
  const float* Wk    = (const float*)d_in[4];
  const float* bk    = (const float*)d_in[5];
  const float* Wv    = (const float*)d_in[6];
  const float* bv    = (const float*)d_in[7];
  const float* Wo    = (const float*)d_in[8];
  const float* bo    = (const float*)d_in[9];
  const float* We1   = (const float*)d_in[10];
  const float* be1   = (const float*)d_in[11];
  const float* We2   = (const float*)d_in[12];
  const float* be2   = (const float*)d_in[13];
  const float* ebias = (const float*)d_in[14];
  float* out = (float*)d_out;

  char* ws = (char*)d_ws;
  u16*   xb   = (u16*)(ws + 0);          //  4 MB  x bf16 (DEAD after gemm_qkv -> om1)
  u16*   wqkv = (u16*)(ws + 4194304);    //  1.5MB Wq|Wk|Wv bf16 (DEAD after gemm_qkv -> lsp)
  u16*   wob  = (u16*)(ws + 5767168);    //  0.5MB Wo bf16
  u16*   qh   = (u16*)(ws + 6291456);    //  4 MB  (B,H,N,64) row-major
  u16*   ksw  = (u16*)(ws + 10485760);   //  4 MB  fragment-major K
  u16*   vsw  = (u16*)(ws + 14680064);   //  4 MB  fragment-major V
  u16*   om0  = (u16*)(ws + 18874368);   //  4 MB  partial jh=0 (B,N,512) bf16
  float* co   = (float*)(ws + 23068672); //  1 KB  edge coefficients
  u16*   om1  = xb;                      //  4 MB  partial jh=1 (reuses xb)
  float* lsp  = (float*)wqkv;            //  256KB lsum partials (reuses wqkv)
  if (ws_size < 23069696) return;

  prep_kernel<<<3073, 256, 0, stream>>>(x, Wq, Wk, Wv, Wo, We1, be1, We2, be2, ebias,
                                        xb, wqkv, wob, co);
  gemm_qkv_kernel<<<dim3(12, 64), 256, 0, stream>>>(xb, wqkv, bq, bk, bv, qh, ksw, vsw);
  flash_kernel<<<dim3(32, NH, NB * 2), 256, 0, stream>>>(qh, ksw, vsw, adj, co,
                                                         om0, om1, lsp);
  gemm_out_kernel<<<dim3(8, 64), 256, 0, stream>>>(om0, om1, lsp, wob, bo, out);
}